// Round 1
// baseline (253.027 us; speedup 1.0000x reference)
//
#include <hip/hip_runtime.h>

typedef __attribute__((ext_vector_type(8))) short short8;
typedef __attribute__((ext_vector_type(4))) float float4f;

#define PITCH 136   // shorts/row in LDS planes
#define LOG_SLOPE -2.302585092994046f   // log(0.1)
#define LN2 0.6931471805599453f
#define NBLK 268    // 12 LU + 256 fwd (16 rows per fwd block, single wave)
#define LDS_BYTES 26112   // 6 planes * 16*136*2 (LU needs 8192 of it)
// ws layout (floats): [0] ticket | [2..13] logdet partials | [64..4159] counts
// [4160..5695] fp32 biases | [8192..] W hi/lo ushort planes
#define WS_BIAS 4160
#define WS_WPLANES 8192
#define NWELEM 196608   // 12 * 16384

__device__ __forceinline__ float bf2f(unsigned int u) {
    return __builtin_bit_cast(float, u << 16);
}
__device__ __forceinline__ unsigned short f2bf(float f) {
    unsigned int x = __builtin_bit_cast(unsigned int, f);
    x += 0x7fff + ((x >> 16) & 1);   // round-to-nearest-even
    return (unsigned short)(x >> 16);
}
__device__ __forceinline__ float4f vmsub(float4f a, float s, float4f b) {
    a[0] -= s * b[0]; a[1] -= s * b[1]; a[2] -= s * b[2]; a[3] -= s * b[3];
    return a;
}

template<int ISF32>
__device__ __forceinline__ float ldv(const void* p, int i) {
    if (ISF32) return ((const float*)p)[i];
    return bf2f(((const unsigned short*)p)[i]);
}

// Per-wave dtype sniff: fp32 weights read as u16 pairs have uniform-random
// mantissa halves; bf16 weights have exponent fields in a narrow band.
__device__ __forceinline__ int detect_f32(const unsigned short* W1u, int lane) {
    unsigned int u = W1u[lane * 2];
    unsigned int e = (u >> 7) & 0xFF;
    int bad = (e < 64) || (e > 135);
    return __ballot(bad) != 0ull;
}

__device__ __forceinline__ float4f mfma16(short8 a, short8 b, float4f c) {
    return __builtin_amdgcn_mfma_f32_16x16x32_bf16(a, b, c, 0, 0, 0);
}

__device__ __forceinline__ void split8(float4f a, float4f b, short8& hi, short8& lo) {
#pragma unroll
    for (int j = 0; j < 4; ++j) {
        float v = a[j]; unsigned short h = f2bf(v);
        hi[j] = (short)h; lo[j] = (short)f2bf(v - bf2f(h));
        v = b[j]; h = f2bf(v);
        hi[4 + j] = (short)h; lo[4 + j] = (short)f2bf(v - bf2f(h));
    }
}

// ---- prep: W -> bf16 hi/lo planes, biases -> fp32, zero ticket ----
__global__ void k_prep(const void* __restrict__ W1, const void* __restrict__ W2,
                       const void* __restrict__ W3, const void* __restrict__ b1,
                       const void* __restrict__ b2, const void* __restrict__ b3,
                       float* __restrict__ ws) {
    const int tid = threadIdx.x, bid = blockIdx.x;
    const int isf32 = detect_f32((const unsigned short*)W1, tid & 63);
    unsigned short* whi = (unsigned short*)(ws + WS_WPLANES);
    unsigned short* wlo = whi + NWELEM;
    if (bid < 96) {
        int s = (bid * 256 + tid) * 8;        // 96*256*8 = 196608
        int mat = s >> 14, off = s & 16383;   // mat = wsel*4 + layer
        int wsel = mat >> 2;
        const void* Wm = wsel == 0 ? W1 : (wsel == 1 ? W2 : W3);
        int src = (mat & 3) * 16384 + off;
        short8 hi, lo;
        if (isf32) {
            const float* p = (const float*)Wm + src;
            split8(*(const float4f*)p, *(const float4f*)(p + 4), hi, lo);
        } else {
            hi = *(const short8*)((const unsigned short*)Wm + src);
            lo = (short8){0, 0, 0, 0, 0, 0, 0, 0};
        }
        *(short8*)(whi + s) = hi;
        *(short8*)(wlo + s) = lo;
    } else {
        for (int e = tid; e < 1536; e += 256) {
            int bsel = e >> 9, idx = e & 511;
            const void* bp = bsel == 0 ? b1 : (bsel == 1 ? b2 : b3);
            ws[WS_BIAS + e] = isf32 ? ((const float*)bp)[idx]
                                    : bf2f(((const unsigned short*)bp)[idx]);
        }
        if (tid == 0) ((int*)ws)[0] = 0;   // finalize ticket
    }
}

// Load one 16-col weight tile (hi+lo) into 8 short8 slots. All static offsets.
__device__ __forceinline__ void loadTile(short8* d,
                                         const unsigned short* __restrict__ wh,
                                         const unsigned short* __restrict__ wl,
                                         int ct, int m, int q) {
    const unsigned short* ph = wh + (ct * 16 + m) * 128 + q * 8;
    const unsigned short* pl = wl + (ct * 16 + m) * 128 + q * 8;
#pragma unroll
    for (int kk = 0; kk < 4; ++kk) {
        d[kk * 2 + 0] = *(const short8*)(ph + kk * 32);
        d[kk * 2 + 1] = *(const short8*)(pl + kk * 32);
    }
}

// Single-wave matvec: out[16x128] = f(in[16x128] @ W^T + bias). No barriers:
// same-wave LDS RAW is ordered by compiler lgkmcnt. Wb holds 4 weight tiles
// (128 VGPR); pairs are consumed/refilled rolling: entry invariant = slots
// 0..3 hold tiles 0..3 of the CURRENT matrix; exit = tiles 0..3 of NEXT.
// MODE 0: out=leaky(v) | 1: v+=res(regs), res=v, write | 2: leaky+count | 3: count only
template<int MODE>
__device__ __forceinline__ void matvec(
        const unsigned short* __restrict__ inh, const unsigned short* __restrict__ inl,
        unsigned short* outh, unsigned short* outl,
        const unsigned short* __restrict__ cwh, const unsigned short* __restrict__ cwl,
        const unsigned short* __restrict__ nwh, const unsigned short* __restrict__ nwl,
        const float* __restrict__ bias,
        float4f* res, int* cnt, short8* Wb, int m, int q) {
    short8 xh[4], xl[4];
#pragma unroll
    for (int kk = 0; kk < 4; ++kk) {
        xh[kk] = *(const short8*)(inh + m * PITCH + kk * 32 + q * 8);
        xl[kk] = *(const short8*)(inl + m * PITCH + kk * 32 + q * 8);
    }
    float bv[8];
#pragma unroll
    for (int ct = 0; ct < 8; ++ct) bv[ct] = bias[ct * 16 + m];
    float4f acc[8];
#pragma unroll
    for (int ct = 0; ct < 8; ++ct) acc[ct] = (float4f){0.f, 0.f, 0.f, 0.f};
#pragma unroll
    for (int p = 0; p < 4; ++p) {
        const int t0 = 2 * p, t1 = 2 * p + 1;
        const int s0 = (p & 1) * 16, s1 = s0 + 8;   // short8 offsets of the 2 slots
        // two independent accumulator chains interleaved to cover MFMA latency
#pragma unroll
        for (int kk = 0; kk < 4; ++kk) {
            acc[t0] = mfma16(xh[kk], Wb[s0 + kk * 2 + 0], acc[t0]);
            acc[t1] = mfma16(xh[kk], Wb[s1 + kk * 2 + 0], acc[t1]);
            acc[t0] = mfma16(xl[kk], Wb[s0 + kk * 2 + 0], acc[t0]);
            acc[t1] = mfma16(xl[kk], Wb[s1 + kk * 2 + 0], acc[t1]);
            acc[t0] = mfma16(xh[kk], Wb[s0 + kk * 2 + 1], acc[t0]);
            acc[t1] = mfma16(xh[kk], Wb[s1 + kk * 2 + 1], acc[t1]);
        }
        // refill the two slots just consumed
        if (p < 2) {
            loadTile(Wb + s0, cwh, cwl, t0 + 4, m, q);
            loadTile(Wb + s1, cwh, cwl, t1 + 4, m, q);
        } else {   // prefetch next matvec's tiles 0..3; latency hides under epilogue
            loadTile(Wb + s0, nwh, nwl, t0 - 4, m, q);
            loadTile(Wb + s1, nwh, nwl, t1 - 4, m, q);
        }
    }
    // epilogue (C layout: row = q*4+r, col = ct*16+m)
#pragma unroll
    for (int ct = 0; ct < 8; ++ct) {
#pragma unroll
        for (int r = 0; r < 4; ++r) {
            float v = acc[ct][r] + bv[ct];
            if (MODE >= 2) cnt[r] += (v <= 0.0f) ? 1 : 0;
            if (MODE == 0 || MODE == 2) v = fmaxf(v, 0.1f * v);  // leaky
            if (MODE == 1) { v += res[ct * 1][r]; res[ct][r] = v; }
            if (MODE != 3) {
                const int o = (q * 4 + r) * PITCH + ct * 16 + m;
                unsigned short h = f2bf(v);
                outh[o] = h;
                outl[o] = f2bf(v - bf2f(h));
            }
        }
    }
}

// Per-wave fwd: 16 rows through 4 blocks x 5 matvecs, residual in fp32 regs,
// counts in regs, zero barriers. Planes: P0=x, P1/P2 = temporaries.
template<int ISF32>
__device__ void fwd(int bid, int lane, char* ldsb,
                    const void* __restrict__ x, const float* __restrict__ ws,
                    void* __restrict__ out, float* __restrict__ wsw) {
    unsigned short* P = (unsigned short*)ldsb;
    unsigned short* P0h = P + 0 * 16 * PITCH;
    unsigned short* P0l = P + 1 * 16 * PITCH;
    unsigned short* P1h = P + 2 * 16 * PITCH;
    unsigned short* P1l = P + 3 * 16 * PITCH;
    unsigned short* P2h = P + 4 * 16 * PITCH;
    unsigned short* P2l = P + 5 * 16 * PITCH;
    const unsigned short* whi = (const unsigned short*)(ws + WS_WPLANES);
    const unsigned short* wlo = whi + NWELEM;
    const float* bias = ws + WS_BIAS;
    const int r0 = bid * 16;
    const int m = lane & 15, q = lane >> 4;

    short8 Wb[32];
    // prologue: W1(layer 0) tiles 0..3
    loadTile(Wb + 0,  whi, wlo, 0, m, q);
    loadTile(Wb + 8,  whi, wlo, 1, m, q);
    loadTile(Wb + 16, whi, wlo, 2, m, q);
    loadTile(Wb + 24, whi, wlo, 3, m, q);

    // residual x in fp32 registers, C-layout
    float4f res[8];
#pragma unroll
    for (int ct = 0; ct < 8; ++ct) {
#pragma unroll
        for (int r = 0; r < 4; ++r)
            res[ct][r] = ldv<ISF32>(x, (r0 + q * 4 + r) * 128 + ct * 16 + m);
    }
    // stage x -> P0 hi/lo
#pragma unroll 4
    for (int e = lane; e < 2048; e += 64) {
        int r = e >> 7, c = e & 127;
        float v = ldv<ISF32>(x, (r0 + r) * 128 + c);
        unsigned short h = f2bf(v);
        P0h[r * PITCH + c] = h;
        P0l[r * PITCH + c] = f2bf(v - bf2f(h));
    }
    int cnt[4] = {0, 0, 0, 0};
#pragma unroll 1
    for (int layer = 0; layer < 4; ++layer) {
        const unsigned short* w1h = whi + (0 + layer) * 16384;
        const unsigned short* w1l = wlo + (0 + layer) * 16384;
        const unsigned short* w2h = whi + (4 + layer) * 16384;
        const unsigned short* w2l = wlo + (4 + layer) * 16384;
        const unsigned short* w3h = whi + (8 + layer) * 16384;
        const unsigned short* w3l = wlo + (8 + layer) * 16384;
        const unsigned short* n1h = whi + ((layer + 1) & 3) * 16384;
        const unsigned short* n1l = wlo + ((layer + 1) & 3) * 16384;
        const float* b1p = bias + layer * 128;
        const float* b2p = bias + 512 + layer * 128;
        const float* b3p = bias + 1024 + layer * 128;
        matvec<0>(P0h, P0l, P1h, P1l, w1h, w1l, w2h, w2l, b1p, res, cnt, Wb, m, q);
        matvec<0>(P1h, P1l, P2h, P2l, w2h, w2l, w3h, w3l, b2p, res, cnt, Wb, m, q);
        matvec<1>(P2h, P2l, P0h, P0l, w3h, w3l, w1h, w1l, b3p, res, cnt, Wb, m, q);
        matvec<2>(P0h, P0l, P1h, P1l, w1h, w1l, w2h, w2l, b1p, res, cnt, Wb, m, q);
        matvec<3>(P1h, P1l, P1h, P1l, w2h, w2l, n1h, n1l, b2p, res, cnt, Wb, m, q);
    }
    // count reduction across the 16-lane col groups (rows q*4+r)
#pragma unroll
    for (int r = 0; r < 4; ++r) {
        int c = cnt[r];
        c += __shfl_xor(c, 1);
        c += __shfl_xor(c, 2);
        c += __shfl_xor(c, 4);
        c += __shfl_xor(c, 8);
        if (m == 0) wsw[64 + r0 + q * 4 + r] = (float)c;
    }
    // final x from fp32 residual regs
#pragma unroll
    for (int ct = 0; ct < 8; ++ct) {
#pragma unroll
        for (int r = 0; r < 4; ++r) {
            float v = res[ct][r];
            const int o = (r0 + q * 4 + r) * 128 + ct * 16 + m;
            if (ISF32) ((float*)out)[o] = v;
            else ((unsigned short*)out)[o] = f2bf(v);
        }
    }
}

// ---- register-resident unpivoted LU, RANK-4 per barrier (32 intervals).
// Unchanged from previous version.
template<int ISF32>
__device__ __forceinline__ float lu_logdet(int id, int tid, float* lds,
        const void* W1, const void* W2, const void* W3) {
    const int wsel = id % 3;
    const void* Wm = (wsel == 0 ? W1 : (wsel == 1 ? W2 : W3));
    const int ofs = (id / 3) * 16384;
    const int tx = tid & 31, ty = tid >> 5;
    float* rowbuf = lds;          // [2][4][128]: rows K..K+3
    float* colbuf = lds + 1024;   // [2][4][128]: cols K..K+3 packed [j][ty*16+m]
    float4f V[16];                // A[ty+8m][4tx..4tx+3]
#pragma unroll
    for (int m = 0; m < 16; ++m) {
        int base = ofs + (ty + 8 * m) * 128 + 4 * tx;
        if (ISF32) {
            V[m] = *(const float4f*)((const float*)Wm + base);
        } else {
            ushort4 u = *(const ushort4*)((const unsigned short*)Wm + base);
            V[m] = (float4f){bf2f(u.x), bf2f(u.y), bf2f(u.z), bf2f(u.w)};
        }
    }
    if (ty < 4) *(float4f*)&rowbuf[ty * 128 + 4 * tx] = V[0];
    if (tx == 0) {
#pragma unroll
        for (int j = 0; j < 4; ++j) {
#pragma unroll
            for (int mg = 0; mg < 4; ++mg) {
                float4f t = {V[mg * 4 + 0][j], V[mg * 4 + 1][j],
                             V[mg * 4 + 2][j], V[mg * 4 + 3][j]};
                *(float4f*)&colbuf[j * 128 + ty * 16 + mg * 4] = t;
            }
        }
    }
    __syncthreads();
    float logacc = 0.0f;
#pragma unroll 1
    for (int kap = 0; kap < 32; ++kap) {
        const int K = kap * 4;
        const int buf = (kap & 1) * 512;
        float4f D[4], R[4], C[4][4];
#pragma unroll
        for (int j = 0; j < 4; ++j) {
            D[j] = *(const float4f*)&rowbuf[buf + j * 128 + K];       // broadcast
            R[j] = *(const float4f*)&rowbuf[buf + j * 128 + 4 * tx];
#pragma unroll
            for (int mg = 0; mg < 4; ++mg)
                C[j][mg] = *(const float4f*)&colbuf[buf + j * 128 + ty * 16 + mg * 4];
        }
        float p0 = D[0][0], i0 = 1.0f / p0;
        float l10 = D[1][0] * i0, l20 = D[2][0] * i0, l30 = D[3][0] * i0;
        D[1] = vmsub(D[1], l10, D[0]); R[1] = vmsub(R[1], l10, R[0]);
        D[2] = vmsub(D[2], l20, D[0]); R[2] = vmsub(R[2], l20, R[0]);
        D[3] = vmsub(D[3], l30, D[0]); R[3] = vmsub(R[3], l30, R[0]);
        float p1 = D[1][1], i1 = 1.0f / p1;
        float l21 = D[2][1] * i1, l31 = D[3][1] * i1;
        D[2] = vmsub(D[2], l21, D[1]); R[2] = vmsub(R[2], l21, R[1]);
        D[3] = vmsub(D[3], l31, D[1]); R[3] = vmsub(R[3], l31, R[1]);
        float p2 = D[2][2], i2 = 1.0f / p2;
        float l32 = D[3][2] * i2;
        D[3] = vmsub(D[3], l32, D[2]); R[3] = vmsub(R[3], l32, R[2]);
        float p3 = D[3][3], i3 = 1.0f / p3;
        logacc += __log2f(fabsf(p0)) + __log2f(fabsf(p1))
                + __log2f(fabsf(p2)) + __log2f(fabsf(p3));
        float iv[4] = {i0, i1, i2, i3};
#pragma unroll
        for (int i = 0; i < 4; ++i) {
#pragma unroll
            for (int mg = 0; mg < 4; ++mg) {
#pragma unroll
                for (int e = 0; e < 4; ++e) {
                    int r = ty + 32 * mg + 8 * e;
                    C[i][mg][e] = (r > K + i) ? C[i][mg][e] * iv[i] : 0.0f;
                }
            }
#pragma unroll
            for (int j = i + 1; j < 4; ++j) {
                float uij = D[i][j];
#pragma unroll
                for (int mg = 0; mg < 4; ++mg)
                    C[j][mg] = vmsub(C[j][mg], uij, C[i][mg]);
            }
        }
#pragma unroll
        for (int mg = 0; mg < 4; ++mg) {
#pragma unroll
            for (int e = 0; e < 4; ++e) {
                float4f v = V[mg * 4 + e];
                v = vmsub(v, C[0][mg][e], R[0]);
                v = vmsub(v, C[1][mg][e], R[1]);
                v = vmsub(v, C[2][mg][e], R[2]);
                v = vmsub(v, C[3][mg][e], R[3]);
                V[mg * 4 + e] = v;
            }
        }
        if (kap < 31) {
            const int nbuf = ((kap + 1) & 1) * 512;
            const int tb = (kap & 1) ? 0 : 4;
            const int mn = (kap + 1) >> 1;
            if (ty >= tb && ty < tb + 4) {
                float4f val;
                switch (mn) {
                case 0:  val = V[0];  break; case 1:  val = V[1];  break;
                case 2:  val = V[2];  break; case 3:  val = V[3];  break;
                case 4:  val = V[4];  break; case 5:  val = V[5];  break;
                case 6:  val = V[6];  break; case 7:  val = V[7];  break;
                case 8:  val = V[8];  break; case 9:  val = V[9];  break;
                case 10: val = V[10]; break; case 11: val = V[11]; break;
                case 12: val = V[12]; break; case 13: val = V[13]; break;
                case 14: val = V[14]; break; default: val = V[15]; break;
                }
                *(float4f*)&rowbuf[nbuf + (ty - tb) * 128 + 4 * tx] = val;
            }
            if (tx == kap + 1) {
#pragma unroll
                for (int j = 0; j < 4; ++j) {
#pragma unroll
                    for (int mg = 0; mg < 4; ++mg) {
                        float4f t = {V[mg * 4 + 0][j], V[mg * 4 + 1][j],
                                     V[mg * 4 + 2][j], V[mg * 4 + 3][j]};
                        *(float4f*)&colbuf[nbuf + j * 128 + ty * 16 + mg * 4] = t;
                    }
                }
            }
        }
        __syncthreads();
    }
    return logacc * LN2;
}

__global__ __launch_bounds__(256, 1) void k_main(
        const void* __restrict__ x,
        const void* __restrict__ W1, const void* __restrict__ b1,
        const void* __restrict__ W2, const void* __restrict__ b2,
        const void* __restrict__ W3, const void* __restrict__ b3,
        void* __restrict__ out, float* __restrict__ ws) {
    extern __shared__ __align__(16) char ldsb[];
    const int tid = threadIdx.x;
    const int lane = tid & 63;
    // fwd blocks: single active wave, waves 1-3 exit before any barrier
    if (blockIdx.x >= 12 && tid >= 64) return;
    const int isf32 = detect_f32((const unsigned short*)W1, lane);

    if (blockIdx.x < 12) {
        float ld = isf32 ? lu_logdet<1>(blockIdx.x, tid, (float*)ldsb, W1, W2, W3)
                         : lu_logdet<0>(blockIdx.x, tid, (float*)ldsb, W1, W2, W3);
        if (tid == 0) ws[2 + blockIdx.x] = ld;
        if (tid >= 64) return;   // only wave 0 continues (no more barriers)
    } else {
        const int bid = blockIdx.x - 12;
        if (isf32) fwd<1>(bid, lane, ldsb, x, ws, out, ws);
        else       fwd<0>(bid, lane, ldsb, x, ws, out, ws);
    }

    // ---- last-block finalize (wave 0 only, wave-level broadcast) ----
    __threadfence();
    int lastf = 0;
    if (lane == 0) lastf = (atomicAdd((int*)ws, 1) == NBLK - 1) ? 1 : 0;
    lastf = __shfl(lastf, 0);
    if (!lastf) return;
    __threadfence();   // acquire: other blocks' ws writes now visible
    float s = 0.0f;
#pragma unroll
    for (int i = 0; i < 12; ++i) s += ws[2 + i];
    for (int b = lane; b < 4096; b += 64) {
        float v = s + LOG_SLOPE * ws[64 + b];
        if (isf32) ((float*)out)[524288 + b] = v;
        else ((unsigned short*)out)[524288 + b] = f2bf(v);
    }
}

extern "C" void kernel_launch(void* const* d_in, const int* in_sizes, int n_in,
                              void* d_out, int out_size, void* d_ws, size_t ws_size,
                              hipStream_t stream) {
    const void* x  = d_in[0];
    const void* W1 = d_in[1];
    const void* b1 = d_in[2];
    const void* W2 = d_in[3];
    const void* b2 = d_in[4];
    const void* W3 = d_in[5];
    const void* b3 = d_in[6];
    float* ws = (float*)d_ws;

    hipLaunchKernelGGL(k_prep, dim3(97), dim3(256), 0, stream,
                       W1, W2, W3, b1, b2, b3, ws);
    hipLaunchKernelGGL(k_main, dim3(NBLK), dim3(256), LDS_BYTES, stream,
                       x, W1, b1, W2, b2, W3, b3, d_out, ws);
}

// Round 2
// 249.822 us; speedup vs baseline: 1.0128x; 1.0128x over previous
//
#include <hip/hip_runtime.h>

typedef __attribute__((ext_vector_type(8))) short short8;
typedef __attribute__((ext_vector_type(4))) float float4f;
typedef __attribute__((ext_vector_type(4))) unsigned short ushort4v;

#define PITCH 136   // shorts/row in LDS planes
#define LOG_SLOPE -2.302585092994046f   // log(0.1)
#define LN2 0.6931471805599453f
#define NBLK 268    // 12 LU + 256 fwd (16 rows per fwd block, single wave)
#define LDS_BYTES 32256   // 6 planes * 16*136*2 + 1536 bias floats
// ws layout (floats): [0] ticket | [2..13] logdet partials | [64..4159] counts
// [4160..5695] fp32 biases | [8192..] W hi/lo ushort planes
#define WS_BIAS 4160
#define WS_WPLANES 8192
#define NWELEM 196608   // 12 * 16384

__device__ __forceinline__ float bf2f(unsigned int u) {
    return __builtin_bit_cast(float, u << 16);
}
__device__ __forceinline__ unsigned short f2bf(float f) {
    unsigned int x = __builtin_bit_cast(unsigned int, f);
    x += 0x7fff + ((x >> 16) & 1);   // round-to-nearest-even
    return (unsigned short)(x >> 16);
}
__device__ __forceinline__ float4f vmsub(float4f a, float s, float4f b) {
    a[0] -= s * b[0]; a[1] -= s * b[1]; a[2] -= s * b[2]; a[3] -= s * b[3];
    return a;
}

template<int ISF32>
__device__ __forceinline__ float ldv(const void* p, int i) {
    if (ISF32) return ((const float*)p)[i];
    return bf2f(((const unsigned short*)p)[i]);
}

// Per-wave dtype sniff: fp32 weights read as u16 pairs have uniform-random
// mantissa halves; bf16 weights have exponent fields in a narrow band.
__device__ __forceinline__ int detect_f32(const unsigned short* W1u, int lane) {
    unsigned int u = W1u[lane * 2];
    unsigned int e = (u >> 7) & 0xFF;
    int bad = (e < 64) || (e > 135);
    return __ballot(bad) != 0ull;
}

__device__ __forceinline__ float4f mfma16(short8 a, short8 b, float4f c) {
    return __builtin_amdgcn_mfma_f32_16x16x32_bf16(a, b, c, 0, 0, 0);
}

__device__ __forceinline__ void split8(float4f a, float4f b, short8& hi, short8& lo) {
#pragma unroll
    for (int j = 0; j < 4; ++j) {
        float v = a[j]; unsigned short h = f2bf(v);
        hi[j] = (short)h; lo[j] = (short)f2bf(v - bf2f(h));
        v = b[j]; h = f2bf(v);
        hi[4 + j] = (short)h; lo[4 + j] = (short)f2bf(v - bf2f(h));
    }
}

// ---- prep: W -> bf16 hi/lo planes, biases -> fp32, zero ticket ----
__global__ void k_prep(const void* __restrict__ W1, const void* __restrict__ W2,
                       const void* __restrict__ W3, const void* __restrict__ b1,
                       const void* __restrict__ b2, const void* __restrict__ b3,
                       float* __restrict__ ws) {
    const int tid = threadIdx.x, bid = blockIdx.x;
    const int isf32 = detect_f32((const unsigned short*)W1, tid & 63);
    unsigned short* whi = (unsigned short*)(ws + WS_WPLANES);
    unsigned short* wlo = whi + NWELEM;
    if (bid < 96) {
        int s = (bid * 256 + tid) * 8;        // 96*256*8 = 196608
        int mat = s >> 14, off = s & 16383;   // mat = wsel*4 + layer
        int wsel = mat >> 2;
        const void* Wm = wsel == 0 ? W1 : (wsel == 1 ? W2 : W3);
        int src = (mat & 3) * 16384 + off;
        short8 hi, lo;
        if (isf32) {
            const float* p = (const float*)Wm + src;
            split8(*(const float4f*)p, *(const float4f*)(p + 4), hi, lo);
        } else {
            hi = *(const short8*)((const unsigned short*)Wm + src);
            lo = (short8){0, 0, 0, 0, 0, 0, 0, 0};
        }
        *(short8*)(whi + s) = hi;
        *(short8*)(wlo + s) = lo;
    } else {
        for (int e = tid; e < 1536; e += 256) {
            int bsel = e >> 9, idx = e & 511;
            const void* bp = bsel == 0 ? b1 : (bsel == 1 ? b2 : b3);
            ws[WS_BIAS + e] = isf32 ? ((const float*)bp)[idx]
                                    : bf2f(((const unsigned short*)bp)[idx]);
        }
        if (tid == 0) ((int*)ws)[0] = 0;   // finalize ticket
    }
}

// Load one 16-col weight tile into a slot. fp32: hi+lo (8 short8, 32 VGPR);
// bf16: hi only (4 short8, 16 VGPR) -- weight lo planes are exactly zero,
// so skipping them is bit-identical.
template<int ISF32>
__device__ __forceinline__ void loadTile(short8* d,
                                         const unsigned short* __restrict__ wh,
                                         const unsigned short* __restrict__ wl,
                                         int ct, int m, int q) {
    const unsigned short* ph = wh + (ct * 16 + m) * 128 + q * 8;
#pragma unroll
    for (int kk = 0; kk < 4; ++kk)
        d[kk * (ISF32 ? 2 : 1)] = *(const short8*)(ph + kk * 32);
    if (ISF32) {
        const unsigned short* pl = wl + (ct * 16 + m) * 128 + q * 8;
#pragma unroll
        for (int kk = 0; kk < 4; ++kk)
            d[kk * 2 + 1] = *(const short8*)(pl + kk * 32);
    }
}

// Single-wave matvec: out[16x128] = f(in[16x128] @ W^T + bias). No barriers:
// same-wave LDS ordering suffices. Wb holds 4 weight tiles, rolling by pairs:
// entry invariant = slots 0..3 hold tiles 0..3 of the CURRENT matrix;
// exit = tiles 0..3 of NEXT. Bias comes from LDS and is folded into acc init.
// MODE 0: out=leaky(v) | 1: v+=res(LDS,=out plane), write | 2: leaky+count | 3: count only
template<int MODE, int ISF32>
__device__ __forceinline__ void matvec(
        const unsigned short* __restrict__ inh, const unsigned short* __restrict__ inl,
        unsigned short* outh, unsigned short* outl,
        const unsigned short* __restrict__ cwh, const unsigned short* __restrict__ cwl,
        const unsigned short* __restrict__ nwh, const unsigned short* __restrict__ nwl,
        const float* __restrict__ bias,
        int* cnt, short8* Wb, int m, int q) {
    const int TS = ISF32 ? 8 : 4;   // short8 slots per tile
    short8 xh[4], xl[4];
#pragma unroll
    for (int kk = 0; kk < 4; ++kk) {
        xh[kk] = *(const short8*)(inh + m * PITCH + kk * 32 + q * 8);
        xl[kk] = *(const short8*)(inl + m * PITCH + kk * 32 + q * 8);
    }
    float4f acc[8];
#pragma unroll
    for (int ct = 0; ct < 8; ++ct) {
        float b = bias[ct * 16 + m];
        acc[ct] = (float4f){b, b, b, b};
    }
#pragma unroll
    for (int p = 0; p < 4; ++p) {
        const int t0 = 2 * p, t1 = 2 * p + 1;
        const int s0 = (p & 1) * 2 * TS, s1 = s0 + TS;
        // two independent accumulator chains interleaved to cover MFMA latency
#pragma unroll
        for (int kk = 0; kk < 4; ++kk) {
            if (ISF32) {
                acc[t0] = mfma16(xh[kk], Wb[s0 + kk * 2 + 0], acc[t0]);
                acc[t1] = mfma16(xh[kk], Wb[s1 + kk * 2 + 0], acc[t1]);
                acc[t0] = mfma16(xl[kk], Wb[s0 + kk * 2 + 0], acc[t0]);
                acc[t1] = mfma16(xl[kk], Wb[s1 + kk * 2 + 0], acc[t1]);
                acc[t0] = mfma16(xh[kk], Wb[s0 + kk * 2 + 1], acc[t0]);
                acc[t1] = mfma16(xh[kk], Wb[s1 + kk * 2 + 1], acc[t1]);
            } else {
                acc[t0] = mfma16(xh[kk], Wb[s0 + kk], acc[t0]);
                acc[t1] = mfma16(xh[kk], Wb[s1 + kk], acc[t1]);
                acc[t0] = mfma16(xl[kk], Wb[s0 + kk], acc[t0]);
                acc[t1] = mfma16(xl[kk], Wb[s1 + kk], acc[t1]);
            }
        }
        // refill the two slots just consumed
        if (p < 2) {
            loadTile<ISF32>(Wb + s0, cwh, cwl, t0 + 4, m, q);
            loadTile<ISF32>(Wb + s1, cwh, cwl, t1 + 4, m, q);
        } else {   // prefetch next matvec's tiles 0..3; latency hides under epilogue
            loadTile<ISF32>(Wb + s0, nwh, nwl, t0 - 4, m, q);
            loadTile<ISF32>(Wb + s1, nwh, nwl, t1 - 4, m, q);
        }
    }
    // epilogue (C layout: row = q*4+r, col = ct*16+m)
#pragma unroll
    for (int ct = 0; ct < 8; ++ct) {
#pragma unroll
        for (int r = 0; r < 4; ++r) {
            float v = acc[ct][r];
            const int o = (q * 4 + r) * PITCH + ct * 16 + m;
            if (MODE == 1) v += bf2f(outh[o]) + bf2f(outl[o]);   // res plane == out plane
            if (MODE >= 2) cnt[r] += (v <= 0.0f) ? 1 : 0;
            if (MODE == 0 || MODE == 2) v = v > 0.0f ? v : 0.1f * v;
            if (MODE != 3) {
                unsigned short h = f2bf(v);
                outh[o] = h;
                outl[o] = f2bf(v - bf2f(h));
            }
        }
    }
}

// Per-wave fwd: 16 rows through 4 layers x 5 matvecs, zero barriers.
// Planes: P0 = x/residual, P1/P2 = temporaries.
template<int ISF32>
__device__ void fwd(int bid, int lane, char* ldsb,
                    const void* __restrict__ x, const float* __restrict__ ws,
                    void* __restrict__ out, float* __restrict__ wsw) {
    unsigned short* P = (unsigned short*)ldsb;
    unsigned short* P0h = P + 0 * 16 * PITCH;
    unsigned short* P0l = P + 1 * 16 * PITCH;
    unsigned short* P1h = P + 2 * 16 * PITCH;
    unsigned short* P1l = P + 3 * 16 * PITCH;
    unsigned short* P2h = P + 4 * 16 * PITCH;
    unsigned short* P2l = P + 5 * 16 * PITCH;
    float* biasL = (float*)(ldsb + 6 * 16 * PITCH * 2);   // 1536 floats
    const unsigned short* whi = (const unsigned short*)(ws + WS_WPLANES);
    const unsigned short* wlo = whi + NWELEM;
    const float* biasG = ws + WS_BIAS;
    const int r0 = bid * 16;
    const int m = lane & 15, q = lane >> 4;
    const int TS = ISF32 ? 8 : 4;

    short8 Wb[ISF32 ? 32 : 16];
    // prologue: layer-0 w1 tiles 0..3 (loads fly while we stage x + biases)
    loadTile<ISF32>(Wb + 0 * TS, whi, wlo, 0, m, q);
    loadTile<ISF32>(Wb + 1 * TS, whi, wlo, 1, m, q);
    loadTile<ISF32>(Wb + 2 * TS, whi, wlo, 2, m, q);
    loadTile<ISF32>(Wb + 3 * TS, whi, wlo, 3, m, q);

    // stage biases -> LDS (read 8x per matvec as cheap ds_read_b32)
#pragma unroll
    for (int e = lane; e < 384; e += 64)
        *(float4f*)&biasL[e * 4] = *(const float4f*)&biasG[e * 4];

    // stage x -> P0 hi/lo (vectorized)
    if (ISF32) {
#pragma unroll
        for (int e = lane; e < 512; e += 64) {
            int r = e >> 5, c = (e & 31) * 4;
            float4f v = *(const float4f*)((const float*)x + (r0 + r) * 128 + c);
            ushort4v h, l;
#pragma unroll
            for (int j = 0; j < 4; ++j) {
                unsigned short hh = f2bf(v[j]);
                h[j] = hh; l[j] = f2bf(v[j] - bf2f(hh));
            }
            *(ushort4v*)(P0h + r * PITCH + c) = h;
            *(ushort4v*)(P0l + r * PITCH + c) = l;
        }
    } else {
        const short8 z = {0, 0, 0, 0, 0, 0, 0, 0};
#pragma unroll
        for (int e = lane; e < 256; e += 64) {
            int r = e >> 4, c = (e & 15) * 8;
            short8 v = *(const short8*)((const unsigned short*)x + (r0 + r) * 128 + c);
            *(short8*)(P0h + r * PITCH + c) = v;
            *(short8*)(P0l + r * PITCH + c) = z;
        }
    }
    int cnt[4] = {0, 0, 0, 0};
#pragma unroll 1
    for (int layer = 0; layer < 4; ++layer) {
        const unsigned short* w1h = whi + (0 + layer) * 16384;
        const unsigned short* w1l = wlo + (0 + layer) * 16384;
        const unsigned short* w2h = whi + (4 + layer) * 16384;
        const unsigned short* w2l = wlo + (4 + layer) * 16384;
        const unsigned short* w3h = whi + (8 + layer) * 16384;
        const unsigned short* w3l = wlo + (8 + layer) * 16384;
        const unsigned short* n1h = whi + ((layer + 1) & 3) * 16384;
        const unsigned short* n1l = wlo + ((layer + 1) & 3) * 16384;
        const float* b1p = biasL + layer * 128;
        const float* b2p = biasL + 512 + layer * 128;
        const float* b3p = biasL + 1024 + layer * 128;
        matvec<0, ISF32>(P0h, P0l, P1h, P1l, w1h, w1l, w2h, w2l, b1p, cnt, Wb, m, q);
        matvec<0, ISF32>(P1h, P1l, P2h, P2l, w2h, w2l, w3h, w3l, b2p, cnt, Wb, m, q);
        matvec<1, ISF32>(P2h, P2l, P0h, P0l, w3h, w3l, w1h, w1l, b3p, cnt, Wb, m, q);
        matvec<2, ISF32>(P0h, P0l, P1h, P1l, w1h, w1l, w2h, w2l, b1p, cnt, Wb, m, q);
        matvec<3, ISF32>(P1h, P1l, P1h, P1l, w2h, w2l, n1h, n1l, b2p, cnt, Wb, m, q);
    }
    // count reduction across the 16-lane col groups (rows q*4+r)
#pragma unroll
    for (int r = 0; r < 4; ++r) {
        int c = cnt[r];
        c += __shfl_xor(c, 1);
        c += __shfl_xor(c, 2);
        c += __shfl_xor(c, 4);
        c += __shfl_xor(c, 8);
        if (m == 0) wsw[64 + r0 + q * 4 + r] = (float)c;
    }
    // final x from P0 hi/lo (vectorized)
    if (ISF32) {
#pragma unroll
        for (int e = lane; e < 512; e += 64) {
            int r = e >> 5, c = (e & 31) * 4;
            ushort4v h = *(const ushort4v*)(P0h + r * PITCH + c);
            ushort4v l = *(const ushort4v*)(P0l + r * PITCH + c);
            float4f v;
#pragma unroll
            for (int j = 0; j < 4; ++j) v[j] = bf2f(h[j]) + bf2f(l[j]);
            *(float4f*)((float*)out + (r0 + r) * 128 + c) = v;
        }
    } else {
#pragma unroll
        for (int e = lane; e < 256; e += 64) {
            int r = e >> 4, c = (e & 15) * 8;
            short8 h = *(const short8*)(P0h + r * PITCH + c);
            short8 l = *(const short8*)(P0l + r * PITCH + c);
            short8 o;
#pragma unroll
            for (int j = 0; j < 8; ++j)
                o[j] = (short)f2bf(bf2f((unsigned short)h[j]) + bf2f((unsigned short)l[j]));
            *(short8*)((unsigned short*)out + (r0 + r) * 128 + c) = o;
        }
    }
}

// ---- register-resident unpivoted LU, RANK-4 per barrier (32 intervals).
template<int ISF32>
__device__ __forceinline__ float lu_logdet(int id, int tid, float* lds,
        const void* W1, const void* W2, const void* W3) {
    const int wsel = id % 3;
    const void* Wm = (wsel == 0 ? W1 : (wsel == 1 ? W2 : W3));
    const int ofs = (id / 3) * 16384;
    const int tx = tid & 31, ty = tid >> 5;
    float* rowbuf = lds;          // [2][4][128]: rows K..K+3
    float* colbuf = lds + 1024;   // [2][4][128]: cols K..K+3 packed [j][ty*16+m]
    float4f V[16];                // A[ty+8m][4tx..4tx+3]
#pragma unroll
    for (int m = 0; m < 16; ++m) {
        int base = ofs + (ty + 8 * m) * 128 + 4 * tx;
        if (ISF32) {
            V[m] = *(const float4f*)((const float*)Wm + base);
        } else {
            ushort4 u = *(const ushort4*)((const unsigned short*)Wm + base);
            V[m] = (float4f){bf2f(u.x), bf2f(u.y), bf2f(u.z), bf2f(u.w)};
        }
    }
    if (ty < 4) *(float4f*)&rowbuf[ty * 128 + 4 * tx] = V[0];
    if (tx == 0) {
#pragma unroll
        for (int j = 0; j < 4; ++j) {
#pragma unroll
            for (int mg = 0; mg < 4; ++mg) {
                float4f t = {V[mg * 4 + 0][j], V[mg * 4 + 1][j],
                             V[mg * 4 + 2][j], V[mg * 4 + 3][j]};
                *(float4f*)&colbuf[j * 128 + ty * 16 + mg * 4] = t;
            }
        }
    }
    __syncthreads();
    float logacc = 0.0f;
#pragma unroll 1
    for (int kap = 0; kap < 32; ++kap) {
        const int K = kap * 4;
        const int buf = (kap & 1) * 512;
        float4f D[4], R[4], C[4][4];
#pragma unroll
        for (int j = 0; j < 4; ++j) {
            D[j] = *(const float4f*)&rowbuf[buf + j * 128 + K];       // broadcast
            R[j] = *(const float4f*)&rowbuf[buf + j * 128 + 4 * tx];
#pragma unroll
            for (int mg = 0; mg < 4; ++mg)
                C[j][mg] = *(const float4f*)&colbuf[buf + j * 128 + ty * 16 + mg * 4];
        }
        float p0 = D[0][0], i0 = 1.0f / p0;
        float l10 = D[1][0] * i0, l20 = D[2][0] * i0, l30 = D[3][0] * i0;
        D[1] = vmsub(D[1], l10, D[0]); R[1] = vmsub(R[1], l10, R[0]);
        D[2] = vmsub(D[2], l20, D[0]); R[2] = vmsub(R[2], l20, R[0]);
        D[3] = vmsub(D[3], l30, D[0]); R[3] = vmsub(R[3], l30, R[0]);
        float p1 = D[1][1], i1 = 1.0f / p1;
        float l21 = D[2][1] * i1, l31 = D[3][1] * i1;
        D[2] = vmsub(D[2], l21, D[1]); R[2] = vmsub(R[2], l21, R[1]);
        D[3] = vmsub(D[3], l31, D[1]); R[3] = vmsub(R[3], l31, R[1]);
        float p2 = D[2][2], i2 = 1.0f / p2;
        float l32 = D[3][2] * i2;
        D[3] = vmsub(D[3], l32, D[2]); R[3] = vmsub(R[3], l32, R[2]);
        float p3 = D[3][3], i3 = 1.0f / p3;
        logacc += __log2f(fabsf(p0)) + __log2f(fabsf(p1))
                + __log2f(fabsf(p2)) + __log2f(fabsf(p3));
        float iv[4] = {i0, i1, i2, i3};
#pragma unroll
        for (int i = 0; i < 4; ++i) {
#pragma unroll
            for (int mg = 0; mg < 4; ++mg) {
#pragma unroll
                for (int e = 0; e < 4; ++e) {
                    int r = ty + 32 * mg + 8 * e;
                    C[i][mg][e] = (r > K + i) ? C[i][mg][e] * iv[i] : 0.0f;
                }
            }
#pragma unroll
            for (int j = i + 1; j < 4; ++j) {
                float uij = D[i][j];
#pragma unroll
                for (int mg = 0; mg < 4; ++mg)
                    C[j][mg] = vmsub(C[j][mg], uij, C[i][mg]);
            }
        }
#pragma unroll
        for (int mg = 0; mg < 4; ++mg) {
#pragma unroll
            for (int e = 0; e < 4; ++e) {
                float4f v = V[mg * 4 + e];
                v = vmsub(v, C[0][mg][e], R[0]);
                v = vmsub(v, C[1][mg][e], R[1]);
                v = vmsub(v, C[2][mg][e], R[2]);
                v = vmsub(v, C[3][mg][e], R[3]);
                V[mg * 4 + e] = v;
            }
        }
        if (kap < 31) {
            const int nbuf = ((kap + 1) & 1) * 512;
            const int tb = (kap & 1) ? 0 : 4;
            const int mn = (kap + 1) >> 1;
            if (ty >= tb && ty < tb + 4) {
                float4f val;
                switch (mn) {
                case 0:  val = V[0];  break; case 1:  val = V[1];  break;
                case 2:  val = V[2];  break; case 3:  val = V[3];  break;
                case 4:  val = V[4];  break; case 5:  val = V[5];  break;
                case 6:  val = V[6];  break; case 7:  val = V[7];  break;
                case 8:  val = V[8];  break; case 9:  val = V[9];  break;
                case 10: val = V[10]; break; case 11: val = V[11]; break;
                case 12: val = V[12]; break; case 13: val = V[13]; break;
                case 14: val = V[14]; break; default: val = V[15]; break;
                }
                *(float4f*)&rowbuf[nbuf + (ty - tb) * 128 + 4 * tx] = val;
            }
            if (tx == kap + 1) {
#pragma unroll
                for (int j = 0; j < 4; ++j) {
#pragma unroll
                    for (int mg = 0; mg < 4; ++mg) {
                        float4f t = {V[mg * 4 + 0][j], V[mg * 4 + 1][j],
                                     V[mg * 4 + 2][j], V[mg * 4 + 3][j]};
                        *(float4f*)&colbuf[nbuf + j * 128 + ty * 16 + mg * 4] = t;
                    }
                }
            }
        }
        __syncthreads();
    }
    return logacc * LN2;
}

__global__ __launch_bounds__(256, 1) void k_main(
        const void* __restrict__ x,
        const void* __restrict__ W1, const void* __restrict__ b1,
        const void* __restrict__ W2, const void* __restrict__ b2,
        const void* __restrict__ W3, const void* __restrict__ b3,
        void* __restrict__ out, float* __restrict__ ws) {
    extern __shared__ __align__(16) char ldsb[];
    const int tid = threadIdx.x;
    const int lane = tid & 63;
    // fwd blocks: single active wave, waves 1-3 exit before any barrier
    if (blockIdx.x >= 12 && tid >= 64) return;
    const int isf32 = detect_f32((const unsigned short*)W1, lane);

    if (blockIdx.x < 12) {
        float ld = isf32 ? lu_logdet<1>(blockIdx.x, tid, (float*)ldsb, W1, W2, W3)
                         : lu_logdet<0>(blockIdx.x, tid, (float*)ldsb, W1, W2, W3);
        if (tid == 0) ws[2 + blockIdx.x] = ld;
        if (tid >= 64) return;   // only wave 0 continues (no more barriers)
    } else {
        const int bid = blockIdx.x - 12;
        if (isf32) fwd<1>(bid, lane, ldsb, x, ws, out, ws);
        else       fwd<0>(bid, lane, ldsb, x, ws, out, ws);
    }

    // ---- last-block finalize (wave 0 only, wave-level broadcast) ----
    __threadfence();
    int lastf = 0;
    if (lane == 0) lastf = (atomicAdd((int*)ws, 1) == NBLK - 1) ? 1 : 0;
    lastf = __shfl(lastf, 0);
    if (!lastf) return;
    __threadfence();   // acquire: other blocks' ws writes now visible
    float s = 0.0f;
#pragma unroll
    for (int i = 0; i < 12; ++i) s += ws[2 + i];
    for (int b = lane; b < 4096; b += 64) {
        float v = s + LOG_SLOPE * ws[64 + b];
        if (isf32) ((float*)out)[524288 + b] = v;
        else ((unsigned short*)out)[524288 + b] = f2bf(v);
    }
}

extern "C" void kernel_launch(void* const* d_in, const int* in_sizes, int n_in,
                              void* d_out, int out_size, void* d_ws, size_t ws_size,
                              hipStream_t stream) {
    const void* x  = d_in[0];
    const void* W1 = d_in[1];
    const void* b1 = d_in[2];
    const void* W2 = d_in[3];
    const void* b2 = d_in[4];
    const void* W3 = d_in[5];
    const void* b3 = d_in[6];
    float* ws = (float*)d_ws;

    hipLaunchKernelGGL(k_prep, dim3(97), dim3(256), 0, stream,
                       W1, W2, W3, b1, b2, b3, ws);
    hipLaunchKernelGGL(k_main, dim3(NBLK), dim3(256), LDS_BYTES, stream,
                       x, W1, b1, W2, b2, W3, b3, d_out, ws);
}

// Round 3
// 248.780 us; speedup vs baseline: 1.0171x; 1.0042x over previous
//
#include <hip/hip_runtime.h>

typedef __attribute__((ext_vector_type(8))) short short8;
typedef __attribute__((ext_vector_type(4))) float float4f;
typedef __attribute__((ext_vector_type(4))) unsigned short ushort4v;

#define PITCH 136   // shorts/row in LDS planes
#define LOG_SLOPE -2.302585092994046f   // log(0.1)
#define LN2 0.6931471805599453f
#define NBLK 268    // 12 LU + 256 fwd (16 rows per fwd block, single wave)
#define LDS_BYTES 32256   // 6 planes * 16*136*2 + 1536 bias floats
// ws layout (floats): [0] ticket | [2..13] logdet partials | [64..4159] counts
// [4160..5695] fp32 biases | [8192..] W hi/lo ushort planes
#define WS_BIAS 4160
#define WS_WPLANES 8192
#define NWELEM 196608   // 12 * 16384

__device__ __forceinline__ float bf2f(unsigned int u) {
    return __builtin_bit_cast(float, u << 16);
}
__device__ __forceinline__ unsigned short f2bf(float f) {
    unsigned int x = __builtin_bit_cast(unsigned int, f);
    x += 0x7fff + ((x >> 16) & 1);   // round-to-nearest-even
    return (unsigned short)(x >> 16);
}
__device__ __forceinline__ float4f vmsub(float4f a, float s, float4f b) {
    a[0] -= s * b[0]; a[1] -= s * b[1]; a[2] -= s * b[2]; a[3] -= s * b[3];
    return a;
}

template<int ISF32>
__device__ __forceinline__ float ldv(const void* p, int i) {
    if (ISF32) return ((const float*)p)[i];
    return bf2f(((const unsigned short*)p)[i]);
}

// Per-wave dtype sniff: fp32 weights read as u16 pairs have uniform-random
// mantissa halves; bf16 weights have exponent fields in a narrow band.
__device__ __forceinline__ int detect_f32(const unsigned short* W1u, int lane) {
    unsigned int u = W1u[lane * 2];
    unsigned int e = (u >> 7) & 0xFF;
    int bad = (e < 64) || (e > 135);
    return __ballot(bad) != 0ull;
}

__device__ __forceinline__ float4f mfma16(short8 a, short8 b, float4f c) {
    return __builtin_amdgcn_mfma_f32_16x16x32_bf16(a, b, c, 0, 0, 0);
}

__device__ __forceinline__ void split8(float4f a, float4f b, short8& hi, short8& lo) {
#pragma unroll
    for (int j = 0; j < 4; ++j) {
        float v = a[j]; unsigned short h = f2bf(v);
        hi[j] = (short)h; lo[j] = (short)f2bf(v - bf2f(h));
        v = b[j]; h = f2bf(v);
        hi[4 + j] = (short)h; lo[4 + j] = (short)f2bf(v - bf2f(h));
    }
}

// ---- prep: W -> bf16 hi/lo planes, biases -> fp32, zero ticket ----
__global__ void k_prep(const void* __restrict__ W1, const void* __restrict__ W2,
                       const void* __restrict__ W3, const void* __restrict__ b1,
                       const void* __restrict__ b2, const void* __restrict__ b3,
                       float* __restrict__ ws) {
    const int tid = threadIdx.x, bid = blockIdx.x;
    const int isf32 = detect_f32((const unsigned short*)W1, tid & 63);
    unsigned short* whi = (unsigned short*)(ws + WS_WPLANES);
    unsigned short* wlo = whi + NWELEM;
    if (bid < 96) {
        int s = (bid * 256 + tid) * 8;        // 96*256*8 = 196608
        int mat = s >> 14, off = s & 16383;   // mat = wsel*4 + layer
        int wsel = mat >> 2;
        const void* Wm = wsel == 0 ? W1 : (wsel == 1 ? W2 : W3);
        int src = (mat & 3) * 16384 + off;
        short8 hi, lo;
        if (isf32) {
            const float* p = (const float*)Wm + src;
            split8(*(const float4f*)p, *(const float4f*)(p + 4), hi, lo);
        } else {
            hi = *(const short8*)((const unsigned short*)Wm + src);
            lo = (short8){0, 0, 0, 0, 0, 0, 0, 0};
        }
        *(short8*)(whi + s) = hi;
        *(short8*)(wlo + s) = lo;
    } else {
        for (int e = tid; e < 1536; e += 256) {
            int bsel = e >> 9, idx = e & 511;
            const void* bp = bsel == 0 ? b1 : (bsel == 1 ? b2 : b3);
            ws[WS_BIAS + e] = isf32 ? ((const float*)bp)[idx]
                                    : bf2f(((const unsigned short*)bp)[idx]);
        }
        if (tid == 0) ((int*)ws)[0] = 0;   // finalize ticket
    }
}

// Load one 16-col weight tile into a slot. fp32: hi+lo (8 short8, 32 VGPR);
// bf16: hi only (4 short8, 16 VGPR) -- weight lo planes are exactly zero,
// so skipping them is bit-identical.
template<int ISF32>
__device__ __forceinline__ void loadTile(short8* d,
                                         const unsigned short* __restrict__ wh,
                                         const unsigned short* __restrict__ wl,
                                         int ct, int m, int q) {
    const unsigned short* ph = wh + (ct * 16 + m) * 128 + q * 8;
#pragma unroll
    for (int kk = 0; kk < 4; ++kk)
        d[kk * (ISF32 ? 2 : 1)] = *(const short8*)(ph + kk * 32);
    if (ISF32) {
        const unsigned short* pl = wl + (ct * 16 + m) * 128 + q * 8;
#pragma unroll
        for (int kk = 0; kk < 4; ++kk)
            d[kk * 2 + 1] = *(const short8*)(pl + kk * 32);
    }
}

// Single-wave matvec: out[16x128] = f(in[16x128] @ W^T + bias). No barriers:
// same-wave LDS ordering suffices. Wb = 3 rolling tile slots (fp32 96 VGPR /
// bf16 48 VGPR). Uniform period-8 schedule, entry/exit invariant:
// slot j holds tile j of the CURRENT matrix (j=0,1,2, in flight ok).
//   compute tile t from slot t%3; t<5: load tile t+3 -> slot t%3
//   t=5: load NEXT tile2 -> slot2 | t=6: NEXT tile0 -> slot0 | t=7: NEXT tile1 -> slot1
// Each slot is reloaded only after its last tile is consumed; boundary loads get
// >=1 tile + epilogue of latency slack.
// MODE 0: out=leaky(v) | 1: v+=res(LDS,=out plane), write | 2: leaky+count | 3: count only
template<int MODE, int ISF32>
__device__ __forceinline__ void matvec(
        const unsigned short* __restrict__ inh, const unsigned short* __restrict__ inl,
        unsigned short* outh, unsigned short* outl,
        const unsigned short* __restrict__ cwh, const unsigned short* __restrict__ cwl,
        const unsigned short* __restrict__ nwh, const unsigned short* __restrict__ nwl,
        const float* __restrict__ bias,
        int* cnt, short8* Wb, int m, int q) {
    const int TS = ISF32 ? 8 : 4;   // short8 slots per tile
    short8 xh[4], xl[4];
#pragma unroll
    for (int kk = 0; kk < 4; ++kk) {
        xh[kk] = *(const short8*)(inh + m * PITCH + kk * 32 + q * 8);
        xl[kk] = *(const short8*)(inl + m * PITCH + kk * 32 + q * 8);
    }
    float4f acc[8];
#pragma unroll
    for (int ct = 0; ct < 8; ++ct) {
        float b = bias[ct * 16 + m];
        acc[ct] = (float4f){b, b, b, b};
    }
#pragma unroll
    for (int t = 0; t < 8; ++t) {
        const int s = (t % 3) * TS;
#pragma unroll
        for (int kk = 0; kk < 4; ++kk) {
            if (ISF32) {
                acc[t] = mfma16(xh[kk], Wb[s + kk * 2 + 0], acc[t]);
                acc[t] = mfma16(xl[kk], Wb[s + kk * 2 + 0], acc[t]);
                acc[t] = mfma16(xh[kk], Wb[s + kk * 2 + 1], acc[t]);
            } else {
                acc[t] = mfma16(xh[kk], Wb[s + kk], acc[t]);
                acc[t] = mfma16(xl[kk], Wb[s + kk], acc[t]);
            }
        }
        if (t < 5) {
            loadTile<ISF32>(Wb + s, cwh, cwl, t + 3, m, q);
        } else {
            const int nt = (t == 5) ? 2 : (t - 6);   // 5->2, 6->0, 7->1
            loadTile<ISF32>(Wb + s, nwh, nwl, nt, m, q);
        }
    }
    // epilogue (C layout: row = q*4+r, col = ct*16+m)
#pragma unroll
    for (int ct = 0; ct < 8; ++ct) {
#pragma unroll
        for (int r = 0; r < 4; ++r) {
            float v = acc[ct][r];
            const int o = (q * 4 + r) * PITCH + ct * 16 + m;
            if (MODE == 1) v += bf2f(outh[o]) + bf2f(outl[o]);   // res plane == out plane
            if (MODE >= 2) cnt[r] += (v <= 0.0f) ? 1 : 0;
            if (MODE == 0 || MODE == 2) v = v > 0.0f ? v : 0.1f * v;
            if (MODE != 3) {
                unsigned short h = f2bf(v);
                outh[o] = h;
                outl[o] = f2bf(v - bf2f(h));
            }
        }
    }
}

// Per-wave fwd: 16 rows through 4 layers x 5 matvecs, zero barriers.
// Planes: P0 = x/residual, P1/P2 = temporaries.
template<int ISF32>
__device__ void fwd(int bid, int lane, char* ldsb,
                    const void* __restrict__ x, const float* __restrict__ ws,
                    void* __restrict__ out, float* __restrict__ wsw) {
    unsigned short* P = (unsigned short*)ldsb;
    unsigned short* P0h = P + 0 * 16 * PITCH;
    unsigned short* P0l = P + 1 * 16 * PITCH;
    unsigned short* P1h = P + 2 * 16 * PITCH;
    unsigned short* P1l = P + 3 * 16 * PITCH;
    unsigned short* P2h = P + 4 * 16 * PITCH;
    unsigned short* P2l = P + 5 * 16 * PITCH;
    float* biasL = (float*)(ldsb + 6 * 16 * PITCH * 2);   // 1536 floats
    const unsigned short* whi = (const unsigned short*)(ws + WS_WPLANES);
    const unsigned short* wlo = whi + NWELEM;
    const float* biasG = ws + WS_BIAS;
    const int r0 = bid * 16;
    const int m = lane & 15, q = lane >> 4;
    const int TS = ISF32 ? 8 : 4;

    short8 Wb[ISF32 ? 24 : 12];
    // prologue: layer-0 w1 tiles 0..2 -> slots 0..2 (fly while staging x + biases)
    loadTile<ISF32>(Wb + 0 * TS, whi, wlo, 0, m, q);
    loadTile<ISF32>(Wb + 1 * TS, whi, wlo, 1, m, q);
    loadTile<ISF32>(Wb + 2 * TS, whi, wlo, 2, m, q);

    // stage biases -> LDS (read 8x per matvec as cheap ds_read_b32)
#pragma unroll
    for (int e = lane; e < 384; e += 64)
        *(float4f*)&biasL[e * 4] = *(const float4f*)&biasG[e * 4];

    // stage x -> P0 hi/lo (vectorized)
    if (ISF32) {
#pragma unroll
        for (int e = lane; e < 512; e += 64) {
            int r = e >> 5, c = (e & 31) * 4;
            float4f v = *(const float4f*)((const float*)x + (r0 + r) * 128 + c);
            ushort4v h, l;
#pragma unroll
            for (int j = 0; j < 4; ++j) {
                unsigned short hh = f2bf(v[j]);
                h[j] = hh; l[j] = f2bf(v[j] - bf2f(hh));
            }
            *(ushort4v*)(P0h + r * PITCH + c) = h;
            *(ushort4v*)(P0l + r * PITCH + c) = l;
        }
    } else {
        const short8 z = {0, 0, 0, 0, 0, 0, 0, 0};
#pragma unroll
        for (int e = lane; e < 256; e += 64) {
            int r = e >> 4, c = (e & 15) * 8;
            short8 v = *(const short8*)((const unsigned short*)x + (r0 + r) * 128 + c);
            *(short8*)(P0h + r * PITCH + c) = v;
            *(short8*)(P0l + r * PITCH + c) = z;
        }
    }
    int cnt[4] = {0, 0, 0, 0};
#pragma unroll 1
    for (int layer = 0; layer < 4; ++layer) {
        const unsigned short* w1h = whi + (0 + layer) * 16384;
        const unsigned short* w1l = wlo + (0 + layer) * 16384;
        const unsigned short* w2h = whi + (4 + layer) * 16384;
        const unsigned short* w2l = wlo + (4 + layer) * 16384;
        const unsigned short* w3h = whi + (8 + layer) * 16384;
        const unsigned short* w3l = wlo + (8 + layer) * 16384;
        const unsigned short* n1h = whi + ((layer + 1) & 3) * 16384;
        const unsigned short* n1l = wlo + ((layer + 1) & 3) * 16384;
        const float* b1p = biasL + layer * 128;
        const float* b2p = biasL + 512 + layer * 128;
        const float* b3p = biasL + 1024 + layer * 128;
        matvec<0, ISF32>(P0h, P0l, P1h, P1l, w1h, w1l, w2h, w2l, b1p, cnt, Wb, m, q);
        matvec<0, ISF32>(P1h, P1l, P2h, P2l, w2h, w2l, w3h, w3l, b2p, cnt, Wb, m, q);
        matvec<1, ISF32>(P2h, P2l, P0h, P0l, w3h, w3l, w1h, w1l, b3p, cnt, Wb, m, q);
        matvec<2, ISF32>(P0h, P0l, P1h, P1l, w1h, w1l, w2h, w2l, b1p, cnt, Wb, m, q);
        matvec<3, ISF32>(P1h, P1l, P1h, P1l, w2h, w2l, n1h, n1l, b2p, cnt, Wb, m, q);
    }
    // count reduction across the 16-lane col groups (rows q*4+r)
#pragma unroll
    for (int r = 0; r < 4; ++r) {
        int c = cnt[r];
        c += __shfl_xor(c, 1);
        c += __shfl_xor(c, 2);
        c += __shfl_xor(c, 4);
        c += __shfl_xor(c, 8);
        if (m == 0) wsw[64 + r0 + q * 4 + r] = (float)c;
    }
    // final x from P0 hi/lo (vectorized)
    if (ISF32) {
#pragma unroll
        for (int e = lane; e < 512; e += 64) {
            int r = e >> 5, c = (e & 31) * 4;
            ushort4v h = *(const ushort4v*)(P0h + r * PITCH + c);
            ushort4v l = *(const ushort4v*)(P0l + r * PITCH + c);
            float4f v;
#pragma unroll
            for (int j = 0; j < 4; ++j) v[j] = bf2f(h[j]) + bf2f(l[j]);
            *(float4f*)((float*)out + (r0 + r) * 128 + c) = v;
        }
    } else {
#pragma unroll
        for (int e = lane; e < 256; e += 64) {
            int r = e >> 4, c = (e & 15) * 8;
            short8 h = *(const short8*)(P0h + r * PITCH + c);
            short8 l = *(const short8*)(P0l + r * PITCH + c);
            short8 o;
#pragma unroll
            for (int j = 0; j < 8; ++j)
                o[j] = (short)f2bf(bf2f((unsigned short)h[j]) + bf2f((unsigned short)l[j]));
            *(short8*)((unsigned short*)out + (r0 + r) * 128 + c) = o;
        }
    }
}

// ---- register-resident unpivoted LU, RANK-4 per barrier (32 intervals).
template<int ISF32>
__device__ __forceinline__ float lu_logdet(int id, int tid, float* lds,
        const void* W1, const void* W2, const void* W3) {
    const int wsel = id % 3;
    const void* Wm = (wsel == 0 ? W1 : (wsel == 1 ? W2 : W3));
    const int ofs = (id / 3) * 16384;
    const int tx = tid & 31, ty = tid >> 5;
    float* rowbuf = lds;          // [2][4][128]: rows K..K+3
    float* colbuf = lds + 1024;   // [2][4][128]: cols K..K+3 packed [j][ty*16+m]
    float4f V[16];                // A[ty+8m][4tx..4tx+3]
#pragma unroll
    for (int m = 0; m < 16; ++m) {
        int base = ofs + (ty + 8 * m) * 128 + 4 * tx;
        if (ISF32) {
            V[m] = *(const float4f*)((const float*)Wm + base);
        } else {
            ushort4 u = *(const ushort4*)((const unsigned short*)Wm + base);
            V[m] = (float4f){bf2f(u.x), bf2f(u.y), bf2f(u.z), bf2f(u.w)};
        }
    }
    if (ty < 4) *(float4f*)&rowbuf[ty * 128 + 4 * tx] = V[0];
    if (tx == 0) {
#pragma unroll
        for (int j = 0; j < 4; ++j) {
#pragma unroll
            for (int mg = 0; mg < 4; ++mg) {
                float4f t = {V[mg * 4 + 0][j], V[mg * 4 + 1][j],
                             V[mg * 4 + 2][j], V[mg * 4 + 3][j]};
                *(float4f*)&colbuf[j * 128 + ty * 16 + mg * 4] = t;
            }
        }
    }
    __syncthreads();
    float logacc = 0.0f;
#pragma unroll 1
    for (int kap = 0; kap < 32; ++kap) {
        const int K = kap * 4;
        const int buf = (kap & 1) * 512;
        float4f D[4], R[4], C[4][4];
#pragma unroll
        for (int j = 0; j < 4; ++j) {
            D[j] = *(const float4f*)&rowbuf[buf + j * 128 + K];       // broadcast
            R[j] = *(const float4f*)&rowbuf[buf + j * 128 + 4 * tx];
#pragma unroll
            for (int mg = 0; mg < 4; ++mg)
                C[j][mg] = *(const float4f*)&colbuf[buf + j * 128 + ty * 16 + mg * 4];
        }
        float p0 = D[0][0], i0 = 1.0f / p0;
        float l10 = D[1][0] * i0, l20 = D[2][0] * i0, l30 = D[3][0] * i0;
        D[1] = vmsub(D[1], l10, D[0]); R[1] = vmsub(R[1], l10, R[0]);
        D[2] = vmsub(D[2], l20, D[0]); R[2] = vmsub(R[2], l20, R[0]);
        D[3] = vmsub(D[3], l30, D[0]); R[3] = vmsub(R[3], l30, R[0]);
        float p1 = D[1][1], i1 = 1.0f / p1;
        float l21 = D[2][1] * i1, l31 = D[3][1] * i1;
        D[2] = vmsub(D[2], l21, D[1]); R[2] = vmsub(R[2], l21, R[1]);
        D[3] = vmsub(D[3], l31, D[1]); R[3] = vmsub(R[3], l31, R[1]);
        float p2 = D[2][2], i2 = 1.0f / p2;
        float l32 = D[3][2] * i2;
        D[3] = vmsub(D[3], l32, D[2]); R[3] = vmsub(R[3], l32, R[2]);
        float p3 = D[3][3], i3 = 1.0f / p3;
        logacc += __log2f(fabsf(p0)) + __log2f(fabsf(p1))
                + __log2f(fabsf(p2)) + __log2f(fabsf(p3));
        float iv[4] = {i0, i1, i2, i3};
#pragma unroll
        for (int i = 0; i < 4; ++i) {
#pragma unroll
            for (int mg = 0; mg < 4; ++mg) {
#pragma unroll
                for (int e = 0; e < 4; ++e) {
                    int r = ty + 32 * mg + 8 * e;
                    C[i][mg][e] = (r > K + i) ? C[i][mg][e] * iv[i] : 0.0f;
                }
            }
#pragma unroll
            for (int j = i + 1; j < 4; ++j) {
                float uij = D[i][j];
#pragma unroll
                for (int mg = 0; mg < 4; ++mg)
                    C[j][mg] = vmsub(C[j][mg], uij, C[i][mg]);
            }
        }
#pragma unroll
        for (int mg = 0; mg < 4; ++mg) {
#pragma unroll
            for (int e = 0; e < 4; ++e) {
                float4f v = V[mg * 4 + e];
                v = vmsub(v, C[0][mg][e], R[0]);
                v = vmsub(v, C[1][mg][e], R[1]);
                v = vmsub(v, C[2][mg][e], R[2]);
                v = vmsub(v, C[3][mg][e], R[3]);
                V[mg * 4 + e] = v;
            }
        }
        if (kap < 31) {
            const int nbuf = ((kap + 1) & 1) * 512;
            const int tb = (kap & 1) ? 0 : 4;
            const int mn = (kap + 1) >> 1;
            if (ty >= tb && ty < tb + 4) {
                float4f val;
                switch (mn) {
                case 0:  val = V[0];  break; case 1:  val = V[1];  break;
                case 2:  val = V[2];  break; case 3:  val = V[3];  break;
                case 4:  val = V[4];  break; case 5:  val = V[5];  break;
                case 6:  val = V[6];  break; case 7:  val = V[7];  break;
                case 8:  val = V[8];  break; case 9:  val = V[9];  break;
                case 10: val = V[10]; break; case 11: val = V[11]; break;
                case 12: val = V[12]; break; case 13: val = V[13]; break;
                case 14: val = V[14]; break; default: val = V[15]; break;
                }
                *(float4f*)&rowbuf[nbuf + (ty - tb) * 128 + 4 * tx] = val;
            }
            if (tx == kap + 1) {
#pragma unroll
                for (int j = 0; j < 4; ++j) {
#pragma unroll
                    for (int mg = 0; mg < 4; ++mg) {
                        float4f t = {V[mg * 4 + 0][j], V[mg * 4 + 1][j],
                                     V[mg * 4 + 2][j], V[mg * 4 + 3][j]};
                        *(float4f*)&colbuf[nbuf + j * 128 + ty * 16 + mg * 4] = t;
                    }
                }
            }
        }
        __syncthreads();
    }
    return logacc * LN2;
}

__global__ __launch_bounds__(256, 1) void k_main(
        const void* __restrict__ x,
        const void* __restrict__ W1, const void* __restrict__ b1,
        const void* __restrict__ W2, const void* __restrict__ b2,
        const void* __restrict__ W3, const void* __restrict__ b3,
        void* __restrict__ out, float* __restrict__ ws) {
    extern __shared__ __align__(16) char ldsb[];
    const int tid = threadIdx.x;
    const int lane = tid & 63;
    // fwd blocks: single active wave, waves 1-3 exit before any barrier
    if (blockIdx.x >= 12 && tid >= 64) return;
    const int isf32 = detect_f32((const unsigned short*)W1, lane);

    if (blockIdx.x < 12) {
        float ld = isf32 ? lu_logdet<1>(blockIdx.x, tid, (float*)ldsb, W1, W2, W3)
                         : lu_logdet<0>(blockIdx.x, tid, (float*)ldsb, W1, W2, W3);
        if (tid == 0) ws[2 + blockIdx.x] = ld;
        if (tid >= 64) return;   // only wave 0 continues (no more barriers)
    } else {
        const int bid = blockIdx.x - 12;
        if (isf32) fwd<1>(bid, lane, ldsb, x, ws, out, ws);
        else       fwd<0>(bid, lane, ldsb, x, ws, out, ws);
    }

    // ---- last-block finalize (wave 0 only, wave-level broadcast) ----
    __threadfence();
    int lastf = 0;
    if (lane == 0) lastf = (atomicAdd((int*)ws, 1) == NBLK - 1) ? 1 : 0;
    lastf = __shfl(lastf, 0);
    if (!lastf) return;
    __threadfence();   // acquire: other blocks' ws writes now visible
    float s = 0.0f;
#pragma unroll
    for (int i = 0; i < 12; ++i) s += ws[2 + i];
    for (int b = lane; b < 4096; b += 64) {
        float v = s + LOG_SLOPE * ws[64 + b];
        if (isf32) ((float*)out)[524288 + b] = v;
        else ((unsigned short*)out)[524288 + b] = f2bf(v);
    }
}

extern "C" void kernel_launch(void* const* d_in, const int* in_sizes, int n_in,
                              void* d_out, int out_size, void* d_ws, size_t ws_size,
                              hipStream_t stream) {
    const void* x  = d_in[0];
    const void* W1 = d_in[1];
    const void* b1 = d_in[2];
    const void* W2 = d_in[3];
    const void* b2 = d_in[4];
    const void* W3 = d_in[5];
    const void* b3 = d_in[6];
    float* ws = (float*)d_ws;

    hipLaunchKernelGGL(k_prep, dim3(97), dim3(256), 0, stream,
                       W1, W2, W3, b1, b2, b3, ws);
    hipLaunchKernelGGL(k_main, dim3(NBLK), dim3(256), LDS_BYTES, stream,
                       x, W1, b1, W2, b2, W3, b3, d_out, ws);
}